// Round 12
// baseline (104.693 us; speedup 1.0000x reference)
//
#include <hip/hip_runtime.h>
#include <hip/hip_fp16.h>

#define NREZ 256
#define NB 8
#define NA 180

// guarded interleaved source: 258x258 pixels of 16B (8 x fp16), 1-px zero border
#define GW 258
#define GBYTES ((size_t)GW * GW * 16)  /* 1,065,024 B */

// Double-buffered LDS tile: 37 rows x LWr stride (LWr in [41,43], per-angle pick
// maximizing oddness of sigma = sn*LWr + cs mod 2 -> linear lane steps spread
// across bank groups). 2 x 37 x 43 x 16B = 50,912B -> 3 blocks/CU.
#define LH 37
#define LWMIN 41
#define LWMAX 43
#define TSTRIDE (LWMAX * LH)  /* 1591 uint4 per buffer */
#define CHUNK_T 16
#define NCHUNK (NREZ / CHUNK_T)

__device__ __forceinline__ __half2 bc_h2(unsigned int v) {
    return __builtin_bit_cast(__half2, v);
}

__device__ __forceinline__ void dma16(const uint4* g, uint4* l) {
    // wave-uniform LDS base; HW scatters active lane i to base + i*16 (verified R6-R11)
    __builtin_amdgcn_global_load_lds(
        (const __attribute__((address_space(1))) void*)g,
        (__attribute__((address_space(3))) void*)l, 16, 0, 0);
}

// interleave 8 batches -> fp16 uint4 pixel at guard offset (+1,+1); border -> 0
__global__ __launch_bounds__(256) void build_fp16g(const float* __restrict__ img,
                                                   uint4* __restrict__ gbuf) {
    const int gy = blockIdx.x;  // 0..257
    for (int gx = threadIdx.x; gx < GW; gx += 256) {
        uint4 v = make_uint4(0u, 0u, 0u, 0u);
        const int x = gx - 1, y = gy - 1;
        if (x >= 0 && x < NREZ && y >= 0 && y < NREZ) {
            const int p = (y << 8) + x;
            unsigned short h[NB];
#pragma unroll
            for (int b = 0; b < NB; ++b)
                h[b] = __half_as_ushort(__float2half_rn(img[b * (NREZ * NREZ) + p]));
            v.x = (unsigned)h[0] | ((unsigned)h[1] << 16);
            v.y = (unsigned)h[2] | ((unsigned)h[3] << 16);
            v.z = (unsigned)h[4] | ((unsigned)h[5] << 16);
            v.w = (unsigned)h[6] | ((unsigned)h[7] << 16);
        }
        gbuf[(size_t)gy * GW + gx] = v;
    }
}

__global__ __launch_bounds__(256, 3) void radon_dma(const uint4* __restrict__ gbuf,
                                                    const float* __restrict__ angles,
                                                    float* __restrict__ out) {
    __shared__ uint4 tile[2 * TSTRIDE];  // 50,912 B

    const int a = blockIdx.x;
    const int tid = threadIdx.x;
    const int wave = tid >> 6;
    const int lane = tid & 63;
    const int ls = lane & 31;   // s within the block's 32-s strip
    const int lp = lane >> 5;   // t phase (0/1)
    const int sIdx = blockIdx.y * 32 + ls;
    const int tw = 2 * wave + lp;  // t-offset 0..7; samples tt = t_lo + tw + 8*it

    const float C = 127.5f;
    float sn, cs;
    sincosf(angles[a], &sn, &cs);

    // per-angle row stride: maximize margin of (sn*LW + cs) mod 2 from even
    int LWr = LWMIN;
    {
        float best = -1.f;
#pragma unroll
        for (int w = LWMIN; w <= LWMAX; ++w) {
            const float sig = fmaf(sn, (float)w, cs);
            const float u = sig - 2.f * floorf(sig * 0.5f);  // [0,2)
            const float m = 1.f - fabsf(u - 1.f);            // 1 = odd (perfect)
            if (m > best) { best = m; LWr = w; }
        }
    }

    const float s = (float)sIdx - C;
    const float xs = fmaf(s, cs, C);  // x = fmaf(tt,-sn,xs)
    const float ys = fmaf(s, sn, C);  // y = fmaf(tt, cs,ys)

    // block-uniform s extremes; SAME fmaf chain as per-lane math (fp-monotone)
    const float s_lo = (float)(blockIdx.y * 32) - C;
    const float s_hi = s_lo + 31.f;
    const float xsl = fmaf(s_lo, cs, C), xsh = fmaf(s_hi, cs, C);
    const float ysl = fmaf(s_lo, sn, C), ysh = fmaf(s_hi, sn, C);

    // chunk = 32 s x 16 t. span <= 31|cs| + 15|sn| <= 34.45 -> u0 in [bx, bx+35],
    // +1 corner -> 36 px -> 37 staged cols/rows always cover (R8-validated geometry).
    // clamp hi = 220 (220 + 36 = 256 = guard row/col). interior: bx,by in [0,219]
    // -> all corners in-image, no per-sample checks.
    auto window = [&](int ck, int& bxs, int& bys, bool& interior, bool& empty, int& hh) {
        const float t_lo = (float)(ck * CHUNK_T) - C;
        const float t_hi = t_lo + 15.f;
        const float x00 = fmaf(t_lo, -sn, xsl), x01 = fmaf(t_hi, -sn, xsl);
        const float x10 = fmaf(t_lo, -sn, xsh), x11 = fmaf(t_hi, -sn, xsh);
        const float y00 = fmaf(t_lo, cs, ysl), y01 = fmaf(t_hi, cs, ysl);
        const float y10 = fmaf(t_lo, cs, ysh), y11 = fmaf(t_hi, cs, ysh);
        const int bx = (int)floorf(fminf(fminf(x00, x01), fminf(x10, x11)));
        const int by = (int)floorf(fminf(fminf(y00, y01), fminf(y10, y11)));
        const int mx = (int)floorf(fmaxf(fmaxf(x00, x01), fmaxf(x10, x11)));
        const int my = (int)floorf(fmaxf(fmaxf(y00, y01), fmaxf(y10, y11)));
        bxs = min(max(bx, -1), 220);
        bys = min(max(by, -1), 220);
        interior = (bx >= 0) && (by >= 0) && (bx <= 219) && (by <= 219);
        empty = (bx > 255) || (by > 255) || (mx < -1) || (my < -1);
        hh = min(LH, max(my - bys + 2, 0));  // rows actually needed
    };

    // stage hh rows x 37 cols into dst; gx,gy in [0,257] of padded source by construction
    auto stage = [&](uint4* dst, int bxs, int bys, int hh) {
#pragma unroll
        for (int k = 0; k < 10; ++k) {
            const int row = wave + 4 * k;  // 0..39
            if (row < hh && lane < 37) {
                const uint4* gp = gbuf + (size_t)(bys + row + 1) * GW + (bxs + 1) + lane;
                dma16(gp, dst + row * LWr);
            }
        }
    };

    float accf[NB];
#pragma unroll
    for (int b = 0; b < NB; ++b) accf[b] = 0.f;
    const __half2 hz = __float2half2_rn(0.f);

    int cbx, cby, chh, nbx, nby, nhh;
    bool cint, cemp, nint, nemp;
    window(0, cbx, cby, cint, cemp, chh);
    if (!cemp) stage(tile, cbx, cby, chh);

    for (int ck = 0; ck < NCHUNK; ++ck) {
        const bool haveNext = (ck + 1 < NCHUNK);
        if (haveNext) window(ck + 1, nbx, nby, nint, nemp, nhh);

        __syncthreads();  // drains DMA(ck) (issued a full compute phase ago);
                          // readers of buf[(ck+1)&1] (chunk ck-1) finished before here

        if (haveNext && !nemp)
            stage(tile + ((ck + 1) & 1) * TSTRIDE, nbx, nby, nhh);  // overlaps compute(ck)

        if (!cemp) {
            const uint4* __restrict__ tl = tile + (ck & 1) * TSTRIDE;
            const float t_lo = (float)(ck * CHUNK_T) - C;
            __half2 acc01 = hz, acc23 = hz, acc45 = hz, acc67 = hz;

            auto samp = [&](float tt, bool chk) {
                const float x = fmaf(tt, -sn, xs);
                const float y = fmaf(tt, cs, ys);
                const float xf = floorf(x), yf = floorf(y);
                const int u0 = (int)xf, v0 = (int)yf;
                if (!chk || (u0 >= -1 && u0 <= 255 && v0 >= -1 && v0 <= 255)) {
                    const float wu = x - xf, wv = y - yf;
                    const float au = 1.f - wu, av = 1.f - wv;
                    const __half2 w00 = __float2half2_rn(au * av);
                    const __half2 w10 = __float2half2_rn(wu * av);
                    const __half2 w01 = __float2half2_rn(au * wv);
                    const __half2 w11 = __float2half2_rn(wu * wv);
                    const int dx = u0 - cbx;  // in [0,35]
                    const int r = v0 - cby;   // in [0,35]
                    const int b00 = r * LWr + dx;
                    const int b10 = b00 + LWr;
                    const uint4 p00 = tl[b00];
                    const uint4 p10 = tl[b00 + 1];
                    const uint4 p01 = tl[b10];
                    const uint4 p11 = tl[b10 + 1];
                    acc01 = __hfma2(w00, bc_h2(p00.x), acc01);
                    acc01 = __hfma2(w10, bc_h2(p10.x), acc01);
                    acc01 = __hfma2(w01, bc_h2(p01.x), acc01);
                    acc01 = __hfma2(w11, bc_h2(p11.x), acc01);
                    acc23 = __hfma2(w00, bc_h2(p00.y), acc23);
                    acc23 = __hfma2(w10, bc_h2(p10.y), acc23);
                    acc23 = __hfma2(w01, bc_h2(p01.y), acc23);
                    acc23 = __hfma2(w11, bc_h2(p11.y), acc23);
                    acc45 = __hfma2(w00, bc_h2(p00.z), acc45);
                    acc45 = __hfma2(w10, bc_h2(p10.z), acc45);
                    acc45 = __hfma2(w01, bc_h2(p01.z), acc45);
                    acc45 = __hfma2(w11, bc_h2(p11.z), acc45);
                    acc67 = __hfma2(w00, bc_h2(p00.w), acc67);
                    acc67 = __hfma2(w10, bc_h2(p10.w), acc67);
                    acc67 = __hfma2(w01, bc_h2(p01.w), acc67);
                    acc67 = __hfma2(w11, bc_h2(p11.w), acc67);
                }
            };

            if (cint) {
                samp(t_lo + (float)tw, false);
                samp(t_lo + (float)(tw + 8), false);
            } else {
                samp(t_lo + (float)tw, true);
                samp(t_lo + (float)(tw + 8), true);
            }

            accf[0] += __low2float(acc01); accf[1] += __high2float(acc01);
            accf[2] += __low2float(acc23); accf[3] += __high2float(acc23);
            accf[4] += __low2float(acc45); accf[5] += __high2float(acc45);
            accf[6] += __low2float(acc67); accf[7] += __high2float(acc67);
        }

        if (haveNext) {
            cbx = nbx; cby = nby; chh = nhh; cint = nint; cemp = nemp;
        }
    }

    // ---- reduction: t-phase pair within wave, then 4 waves via LDS ----
    // Reduction scratch = first 4KB of buf0; last compute (ck=15) read buf1 -> disjoint.
#pragma unroll
    for (int b = 0; b < NB; ++b) accf[b] += __shfl_xor(accf[b], 32);

    float4* red4 = (float4*)tile;
    if (lane < 32) {
        red4[(wave * 32 + lane) * 2 + 0] = make_float4(accf[0], accf[1], accf[2], accf[3]);
        red4[(wave * 32 + lane) * 2 + 1] = make_float4(accf[4], accf[5], accf[6], accf[7]);
    }
    __syncthreads();
    {
        const float* red = (const float*)tile;
        const int b = tid >> 5;   // 0..7
        const int ss = tid & 31;  // 0..31
        const int base = ss * 8 + b;
        const float sum = red[base] + red[256 + base] + red[512 + base] + red[768 + base];
        out[(b * NA + a) * NREZ + blockIdx.y * 32 + ss] = sum;
    }
}

// -------- fallback (ws too small): direct fp32 gather with clamps --------
__global__ __launch_bounds__(256) void radon_plain(const float* __restrict__ img,
                                                   const float* __restrict__ angles,
                                                   float* __restrict__ out) {
    const int a = blockIdx.x;
    const int tid = threadIdx.x;
    const int wave = tid >> 6;
    const int lane = tid & 63;
    const int s_sub = lane & 7;
    const int t_sub = lane >> 3;
    const int sIdx = blockIdx.y * 32 + wave * 8 + s_sub;
    const float c = 127.5f;
    float sn, cs;
    sincosf(angles[a], &sn, &cs);
    const float s = (float)sIdx - c;
    float acc[NB];
#pragma unroll
    for (int b = 0; b < NB; ++b) acc[b] = 0.f;
    for (int j = 0; j < NREZ / 8; ++j) {
        const float tt = (float)(t_sub + 8 * j) - c;
        const float x = s * cs - tt * sn + c;
        const float y = s * sn + tt * cs + c;
        const float xf = floorf(x), yf = floorf(y);
        const int u0 = (int)xf, v0 = (int)yf;
        if (u0 < -1 || u0 >= NREZ || v0 < -1 || v0 >= NREZ) continue;
        const float wu = x - xf, wv = y - yf;
        const bool iu0 = (u0 >= 0), iu1 = (u0 + 1 <= NREZ - 1);
        const bool iv0 = (v0 >= 0), iv1 = (v0 + 1 <= NREZ - 1);
        const float w00 = (1.f - wu) * (1.f - wv) * ((iu0 && iv0) ? 1.f : 0.f);
        const float w10 = wu * (1.f - wv) * ((iu1 && iv0) ? 1.f : 0.f);
        const float w01 = (1.f - wu) * wv * ((iu0 && iv1) ? 1.f : 0.f);
        const float w11 = wu * wv * ((iu1 && iv1) ? 1.f : 0.f);
        const int u0c = min(max(u0, 0), NREZ - 1);
        const int u1c = min(u0 + 1, NREZ - 1);
        const int v0c = min(max(v0, 0), NREZ - 1);
        const int v1c = min(v0 + 1, NREZ - 1);
#pragma unroll
        for (int b = 0; b < NB; ++b) {
            const float* p = img + b * (NREZ * NREZ);
            acc[b] += w00 * p[v0c * NREZ + u0c] + w10 * p[v0c * NREZ + u1c] +
                      w01 * p[v1c * NREZ + u0c] + w11 * p[v1c * NREZ + u1c];
        }
    }
#pragma unroll
    for (int b = 0; b < NB; ++b) {
        float v = acc[b];
        v += __shfl_xor(v, 8);
        v += __shfl_xor(v, 16);
        v += __shfl_xor(v, 32);
        acc[b] = v;
    }
    if (t_sub == 0) {
#pragma unroll
        for (int b = 0; b < NB; ++b) out[(b * NA + a) * NREZ + sIdx] = acc[b];
    }
}

extern "C" void kernel_launch(void* const* d_in, const int* in_sizes, int n_in,
                              void* d_out, int out_size, void* d_ws, size_t ws_size,
                              hipStream_t stream) {
    (void)in_sizes; (void)n_in; (void)out_size;
    const float* imgs = (const float*)d_in[0];
    const float* angles = (const float*)d_in[1];
    float* out = (float*)d_out;

    dim3 grid(NA, NREZ / 32);
    if (ws_size >= GBYTES) {
        uint4* gbuf = (uint4*)d_ws;
        build_fp16g<<<GW, 256, 0, stream>>>(imgs, gbuf);  // fused guard-zeroing
        radon_dma<<<grid, 256, 0, stream>>>(gbuf, angles, out);
    } else {
        radon_plain<<<grid, 256, 0, stream>>>(imgs, angles, out);
    }
}